// Round 1
// baseline (151.951 us; speedup 1.0000x reference)
//
#include <hip/hip_runtime.h>
#include <cstdint>
#include <cstddef>

typedef float v16f __attribute__((ext_vector_type(16)));
typedef short v8s  __attribute__((ext_vector_type(8)));

#define MFMA32(A, B, C) __builtin_amdgcn_mfma_f32_32x32x16_bf16((A), (B), (C), 0, 0, 0)

__device__ __forceinline__ unsigned f2bf(float f) {
  unsigned u = __builtin_bit_cast(unsigned, f);
  u += 0x7FFFu + ((u >> 16) & 1u);
  return u >> 16;
}
__device__ __forceinline__ float bf2f(unsigned us) {
  return __builtin_bit_cast(float, us << 16);
}
__device__ __forceinline__ unsigned sel4(const uint4& v, int h) {
  return h == 0 ? v.x : (h == 1 ? v.y : (h == 2 ? v.z : v.w));
}

// ---------------------------------------------------------------------------
// prep: h = x @ W^T + b (f32 vector), bf16 3-way splits of x, E/F tables,
//       h stored transposed in bf16 (for PV B-operand staging).
// ---------------------------------------------------------------------------
__global__ __launch_bounds__(256) void gat_prep(
    const float* __restrict__ nf, const float* __restrict__ Wm,
    const float* __restrict__ bias, const float* __restrict__ aw,
    unsigned short* __restrict__ nfh, unsigned short* __restrict__ nfm,
    unsigned short* __restrict__ nfl, unsigned short* __restrict__ ht,
    float* __restrict__ EFl, unsigned* __restrict__ EFr)
{
  __shared__ float xl[32][132];
  const int tid = threadIdx.x;
  const int row = tid & 31, g = tid >> 5;
  const int r0 = blockIdx.x * 32;          // global node row base (0..8191)
  const int b = r0 >> 11, n0 = r0 & 2047;
  const int d0 = g * 16;

  float x[16];
  {
    const float* xp = nf + (size_t)(r0 + row) * 128 + d0;
#pragma unroll
    for (int q = 0; q < 4; ++q) {
      float4 v = *(const float4*)(xp + 4 * q);
      x[4*q+0] = v.x; x[4*q+1] = v.y; x[4*q+2] = v.z; x[4*q+3] = v.w;
    }
  }
  unsigned hu[16], mu[16], lu[16];
#pragma unroll
  for (int q = 0; q < 16; ++q) {
    xl[row][d0 + q] = x[q];
    unsigned hb = f2bf(x[q]); float hf = bf2f(hb);
    float r1 = x[q] - hf;
    unsigned mb = f2bf(r1); float mf = bf2f(mb);
    float r2 = r1 - mf;
    unsigned lb = f2bf(r2);
    hu[q] = hb; mu[q] = mb; lu[q] = lb;
  }
  {
    size_t o = (size_t)(r0 + row) * 128 + d0;
    uint4 p0, p1;
    p0.x = hu[0] | (hu[1] << 16);  p0.y = hu[2] | (hu[3] << 16);
    p0.z = hu[4] | (hu[5] << 16);  p0.w = hu[6] | (hu[7] << 16);
    p1.x = hu[8] | (hu[9] << 16);  p1.y = hu[10] | (hu[11] << 16);
    p1.z = hu[12] | (hu[13] << 16); p1.w = hu[14] | (hu[15] << 16);
    *(uint4*)(nfh + o) = p0; *(uint4*)(nfh + o + 8) = p1;
    p0.x = mu[0] | (mu[1] << 16);  p0.y = mu[2] | (mu[3] << 16);
    p0.z = mu[4] | (mu[5] << 16);  p0.w = mu[6] | (mu[7] << 16);
    p1.x = mu[8] | (mu[9] << 16);  p1.y = mu[10] | (mu[11] << 16);
    p1.z = mu[12] | (mu[13] << 16); p1.w = mu[14] | (mu[15] << 16);
    *(uint4*)(nfm + o) = p0; *(uint4*)(nfm + o + 8) = p1;
    p0.x = lu[0] | (lu[1] << 16);  p0.y = lu[2] | (lu[3] << 16);
    p0.z = lu[4] | (lu[5] << 16);  p0.w = lu[6] | (lu[7] << 16);
    p1.x = lu[8] | (lu[9] << 16);  p1.y = lu[10] | (lu[11] << 16);
    p1.z = lu[12] | (lu[13] << 16); p1.w = lu[14] | (lu[15] << 16);
    *(uint4*)(nfl + o) = p0; *(uint4*)(nfl + o + 8) = p1;
  }
  __syncthreads();

  float acc[16];
  const int ob = g * 16;
#pragma unroll
  for (int o = 0; o < 16; ++o) acc[o] = bias[ob + o];
  for (int dd = 0; dd < 128; dd += 4) {
    float4 xq = *(const float4*)&xl[row][dd];
#pragma unroll
    for (int o = 0; o < 16; ++o) {
      float4 wq = *(const float4*)(Wm + (size_t)(ob + o) * 128 + dd);
      acc[o] = fmaf(xq.x, wq.x, acc[o]);
      acc[o] = fmaf(xq.y, wq.y, acc[o]);
      acc[o] = fmaf(xq.z, wq.z, acc[o]);
      acc[o] = fmaf(xq.w, wq.w, acc[o]);
    }
  }
#pragma unroll
  for (int o = 0; o < 16; ++o)
    ht[((size_t)b * 128 + ob + o) * 2048 + n0 + row] = (unsigned short)f2bf(acc[o]);

  const int hh = g >> 1, cb = (g & 1) * 16;
  float sl = 0.f, sr = 0.f;
#pragma unroll
  for (int o = 0; o < 16; ++o) {
    sl = fmaf(acc[o], aw[hh * 64 + cb + o], sl);
    sr = fmaf(acc[o], aw[hh * 64 + 32 + cb + o], sr);
  }
  sl += __shfl_xor(sl, 32, 64);
  sr += __shfl_xor(sr, 32, 64);
  if (!(g & 1)) {
    const float L2E = 1.4426950408889634f;
    float El = exp2f(sl * L2E), Fl = exp2f(sl * (0.3f * L2E));
    float Er = exp2f(sr * L2E), Fr = exp2f(sr * (0.3f * L2E));
    size_t nn = (size_t)(r0 + row);
    EFl[nn * 8 + hh]     = El;
    EFl[nn * 8 + 4 + hh] = Fl;
    EFr[nn * 4 + hh] = (f2bf(Er) << 16) | f2bf(Fr);
  }
}

// ---------------------------------------------------------------------------
// fused attention: per wave one 32-row I-tile, loop over 32-col J-tiles of
// its chunk. S^T via 8-pass split-bf16 MFMA (swapped operands: i = lane&31),
// w = mask ? max(El*Er, Fl*Fr) : 0, P assembled via shfl_xor, PV via MFMA.
// ---------------------------------------------------------------------------
__global__ __launch_bounds__(256, 2) void gat_attn(
    const unsigned short* __restrict__ nfh, const unsigned short* __restrict__ nfm,
    const unsigned short* __restrict__ nfl, const unsigned short* __restrict__ ht,
    const float* __restrict__ EFl, const unsigned* __restrict__ EFr,
    float* __restrict__ nump, float* __restrict__ denp, const int CH)
{
  __shared__ uint4 smem4[2208];   // 35328 B: A-tiles 24576 | V_t 10240 | EF 512
  char* sm = (char*)smem4;
  const int JPC = 2048 / CH, NIT = JPC / 32;

  const int tid  = threadIdx.x;
  const int lane = tid & 63, wv = tid >> 6;
  const int li = lane & 31, hi = lane >> 5;

  const int blk = blockIdx.x;
  const int ig = blk & 15;
  const int t2 = blk >> 4;
  const int ch = t2 % CH;
  const int b  = t2 / CH;

  const size_t nb = (size_t)b * 2048;
  const int i0 = ig * 128 + wv * 32;
  const int j0 = ch * JPC;

  // I-side B-fragments (wave-invariant), 3 split levels
  v8s BH[8], BM[8], BL[8];
  {
    const size_t ro = (nb + i0 + li) * 128 + hi * 8;
#pragma unroll
    for (int kc = 0; kc < 8; ++kc) {
      BH[kc] = *(const v8s*)(nfh + ro + kc * 16);
      BM[kc] = *(const v8s*)(nfm + ro + kc * 16);
      BL[kc] = *(const v8s*)(nfl + ro + kc * 16);
    }
  }
  float EL[4], FL[4];
  {
    const float* p = EFl + (nb + i0 + li) * 8;
    float4 e = *(const float4*)p;
    float4 f = *(const float4*)(p + 4);
    EL[0] = e.x; EL[1] = e.y; EL[2] = e.z; EL[3] = e.w;
    FL[0] = f.x; FL[1] = f.y; FL[2] = f.z; FL[3] = f.w;
  }

  v16f acc[4];
#pragma unroll
  for (int h = 0; h < 4; ++h)
#pragma unroll
    for (int r = 0; r < 16; ++r) acc[h][r] = 0.f;
  float den[4] = {0.f, 0.f, 0.f, 0.f};

  const int srow = tid >> 3, spart = tid & 7;
  const int swz = (srow & 7) << 4;
  const int vrow = tid >> 1, vseg = tid & 1;

  uint4 gA[6], gV[2], gE;

  auto ISSUE = [&](int it) {
    const int j = j0 + it * 32;
    const size_t rb = (nb + j + srow) * 128 + spart * 16;
    gA[0] = *(const uint4*)(nfh + rb);
    gA[1] = *(const uint4*)(nfh + rb + 8);
    gA[2] = *(const uint4*)(nfm + rb);
    gA[3] = *(const uint4*)(nfm + rb + 8);
    gA[4] = *(const uint4*)(nfl + rb);
    gA[5] = *(const uint4*)(nfl + rb + 8);
    const size_t vb = ((size_t)b * 128 + vrow) * 2048 + j + vseg * 16;
    gV[0] = *(const uint4*)(ht + vb);
    gV[1] = *(const uint4*)(ht + vb + 8);
    if (tid < 32) gE = *(const uint4*)(EFr + (nb + j + tid) * 4);
  };
  auto WRITE = [&]() {
    const int rb = srow * 256 + spart * 32;
#pragma unroll
    for (int s = 0; s < 3; ++s) {
      *(uint4*)(sm + ((s * 8192 + rb) ^ swz))      = gA[2 * s];
      *(uint4*)(sm + ((s * 8192 + rb + 16) ^ swz)) = gA[2 * s + 1];
    }
    *(uint4*)(sm + 24576 + vrow * 80 + vseg * 32)      = gV[0];
    *(uint4*)(sm + 24576 + vrow * 80 + vseg * 32 + 16) = gV[1];
    if (tid < 32) *(uint4*)(sm + 34816 + tid * 16) = gE;
  };

  ISSUE(0);
  for (int it = 0; it < NIT; ++it) {
    __syncthreads();              // previous tile fully consumed
    WRITE();
    if (it + 1 < NIT) ISSUE(it + 1);   // hide next tile's HBM latency
    __syncthreads();              // tile ready

    // ---- S^T (8-pass split-bf16) ----
    v16f S;
#pragma unroll
    for (int r = 0; r < 16; ++r) S[r] = 0.f;
    {
      const int ab = li * 256 + hi * 16;
      const int aswz = (li & 7) << 4;
#pragma unroll
      for (int kc = 0; kc < 8; ++kc) {
        const int off = ab + kc * 32;
        v8s AH = *(const v8s*)(sm + ((off) ^ aswz));
        v8s AM = *(const v8s*)(sm + ((8192 + off) ^ aswz));
        v8s AL = *(const v8s*)(sm + ((16384 + off) ^ aswz));
        S = MFMA32(AH, BH[kc], S);
        S = MFMA32(AH, BM[kc], S);
        S = MFMA32(AM, BH[kc], S);
        S = MFMA32(AM, BM[kc], S);
        S = MFMA32(AH, BL[kc], S);
        S = MFMA32(AL, BH[kc], S);
        S = MFMA32(AM, BL[kc], S);
        S = MFMA32(AL, BM[kc], S);
      }
    }

    // ---- w = mask ? max(El*Er, Fl*Fr) : 0, packed to bf16 pairs ----
    unsigned pw[4][8];
#pragma unroll
    for (int rp = 0; rp < 8; ++rp) {
      const int r0i = 2 * rp;
      const int jl0 = (r0i & 3) + 8 * (r0i >> 2) + 4 * hi;
      uint4 e0 = *(const uint4*)(sm + 34816 + jl0 * 16);
      uint4 e1 = *(const uint4*)(sm + 34816 + (jl0 + 1) * 16);
      const bool m0 = S[r0i] > 0.f;
      const bool m1 = S[r0i + 1] > 0.f;
#pragma unroll
      for (int h = 0; h < 4; ++h) {
        const unsigned u0 = sel4(e0, h), u1 = sel4(e1, h);
        float Er0 = __builtin_bit_cast(float, u0 & 0xFFFF0000u);
        float Fr0 = __builtin_bit_cast(float, u0 << 16);
        float Er1 = __builtin_bit_cast(float, u1 & 0xFFFF0000u);
        float Fr1 = __builtin_bit_cast(float, u1 << 16);
        float w0 = fmaxf(Er0 * EL[h], Fr0 * FL[h]); w0 = m0 ? w0 : 0.f;
        float w1 = fmaxf(Er1 * EL[h], Fr1 * FL[h]); w1 = m1 ? w1 : 0.f;
        den[h] += w0 + w1;
        unsigned pk;
        asm("v_cvt_pk_bf16_f32 %0, %1, %2" : "=v"(pk) : "v"(w0), "v"(w1));
        pw[h][rp] = pk;
      }
    }

    // ---- assemble P A-fragments (half-swap via shfl_xor) + PV MFMA ----
#pragma unroll
    for (int h = 0; h < 4; ++h) {
      unsigned x0 = (unsigned)__shfl_xor((int)pw[h][0], 32, 64);
      unsigned x1 = (unsigned)__shfl_xor((int)pw[h][1], 32, 64);
      unsigned x2 = (unsigned)__shfl_xor((int)pw[h][2], 32, 64);
      unsigned x3 = (unsigned)__shfl_xor((int)pw[h][3], 32, 64);
      unsigned x4 = (unsigned)__shfl_xor((int)pw[h][4], 32, 64);
      unsigned x5 = (unsigned)__shfl_xor((int)pw[h][5], 32, 64);
      unsigned x6 = (unsigned)__shfl_xor((int)pw[h][6], 32, 64);
      unsigned x7 = (unsigned)__shfl_xor((int)pw[h][7], 32, 64);
      uint4 c0, c1;
      c0.x = hi ? x2 : pw[h][0];
      c0.y = hi ? x3 : pw[h][1];
      c0.z = hi ? pw[h][2] : x0;
      c0.w = hi ? pw[h][3] : x1;
      c1.x = hi ? x6 : pw[h][4];
      c1.y = hi ? x7 : pw[h][5];
      c1.z = hi ? pw[h][6] : x4;
      c1.w = hi ? pw[h][7] : x5;
      v8s P0 = __builtin_bit_cast(v8s, c0);
      v8s P1 = __builtin_bit_cast(v8s, c1);
      const int vb = 24576 + (h * 32 + li) * 80 + hi * 16;
      v8s V0 = *(const v8s*)(sm + vb);
      v8s V1 = *(const v8s*)(sm + vb + 32);
      acc[h] = MFMA32(P0, V0, acc[h]);
      acc[h] = MFMA32(P1, V1, acc[h]);
    }
  }

#pragma unroll
  for (int h = 0; h < 4; ++h) den[h] += __shfl_xor(den[h], 32, 64);

  const size_t obase = ((size_t)b * CH + ch) * 2048 + i0;
#pragma unroll
  for (int h = 0; h < 4; ++h) {
#pragma unroll
    for (int r = 0; r < 16; ++r) {
      const int il = (r & 3) + 8 * (r >> 2) + 4 * hi;
      nump[(obase + il) * 128 + h * 32 + li] = acc[h][r];
    }
  }
  if (lane < 32) {
    float4 dv;
    dv.x = den[0]; dv.y = den[1]; dv.z = den[2]; dv.w = den[3];
    *(float4*)(denp + (obase + li) * 4) = dv;
  }
}

// ---------------------------------------------------------------------------
// reduce: out = (sum_ch num) / (sum_ch den)
// ---------------------------------------------------------------------------
__global__ __launch_bounds__(256) void gat_reduce(
    const float* __restrict__ nump, const float* __restrict__ denp,
    float* __restrict__ out, const int CH)
{
  const int idx = blockIdx.x * 256 + threadIdx.x;   // < 4*2048*128
  const int b = idx >> 18;
  const int rem = idx & 262143;
  const int n = rem >> 7;
  const int col = rem & 127;
  const int h = col >> 5;
  float s = 0.f, d = 0.f;
  for (int ch = 0; ch < CH; ++ch) {
    s += nump[(((size_t)b * CH + ch) * 2048 + n) * 128 + col];
    d += denp[(((size_t)b * CH + ch) * 2048 + n) * 4 + h];
  }
  out[idx] = s / d;
}

// ---------------------------------------------------------------------------
extern "C" void kernel_launch(void* const* d_in, const int* in_sizes, int n_in,
                              void* d_out, int out_size, void* d_ws, size_t ws_size,
                              hipStream_t stream) {
  const float* nf   = (const float*)d_in[0];
  const float* Wm   = (const float*)d_in[1];
  const float* bias = (const float*)d_in[2];
  const float* aw   = (const float*)d_in[3];
  float* out = (float*)d_out;
  char* ws = (char*)d_ws;

  const size_t S1 = 8192ull * 128 * 2;              // 2 MB per bf16 array
  unsigned short* nfh = (unsigned short*)(ws);
  unsigned short* nfm = (unsigned short*)(ws + S1);
  unsigned short* nfl = (unsigned short*)(ws + 2 * S1);
  unsigned short* ht  = (unsigned short*)(ws + 3 * S1);
  float*    EFl = (float*)(ws + 4 * S1);            // 8192*8*4  = 262144
  unsigned* EFr = (unsigned*)(ws + 4 * S1 + 262144);// 8192*4*4  = 131072
  const size_t fixed = 4 * S1 + 262144 + 131072;    // 8,781,824
  const size_t per = 4194304ull + 131072ull;        // num + den per chunk

  int CH = 1;
  if      (ws_size >= fixed + 8 * per) CH = 8;
  else if (ws_size >= fixed + 4 * per) CH = 4;
  else if (ws_size >= fixed + 2 * per) CH = 2;

  float* denp = (float*)(ws + fixed);
  float* nump = (float*)(ws + fixed + (size_t)CH * 131072);

  gat_prep<<<256, 256, 0, stream>>>(nf, Wm, bias, aw, nfh, nfm, nfl, ht, EFl, EFr);
  gat_attn<<<64 * CH, 256, 0, stream>>>(nfh, nfm, nfl, ht, EFl, EFr, nump, denp, CH);
  gat_reduce<<<4096, 256, 0, stream>>>(nump, denp, out, CH);
}

// Round 2
// 84.768 us; speedup vs baseline: 1.7926x; 1.7926x over previous
//
#include <hip/hip_runtime.h>
#include <cstdint>
#include <cstddef>

typedef float v16f __attribute__((ext_vector_type(16)));
typedef short v8s  __attribute__((ext_vector_type(8)));

#define MFMA32(A,B,C) __builtin_amdgcn_mfma_f32_32x32x16_bf16((A),(B),(C),0,0,0)

__device__ __forceinline__ unsigned f2bf(float f) {
  unsigned u = __builtin_bit_cast(unsigned, f);
  u += 0x7FFFu + ((u >> 16) & 1u);
  return u >> 16;
}
__device__ __forceinline__ float bf2f(unsigned us) {
  return __builtin_bit_cast(float, us << 16);
}
__device__ __forceinline__ unsigned sel4(const uint4& v, int h) {
  return h == 0 ? v.x : (h == 1 ? v.y : (h == 2 ? v.z : v.w));
}
__device__ __forceinline__ void gload16(const void* g, void* l) {
  __builtin_amdgcn_global_load_lds(
      (const __attribute__((address_space(1))) void*)g,
      (__attribute__((address_space(3))) void*)l, 16, 0, 0);
}

// ---------------------------------------------------------------------------
// prep: h = x @ W^T + b (f32 vector), bf16 3-way splits of x, E/F tables,
//       h stored transposed in bf16 (for PV B-operand staging).
// ---------------------------------------------------------------------------
__global__ __launch_bounds__(256) void gat_prep(
    const float* __restrict__ nf, const float* __restrict__ Wm,
    const float* __restrict__ bias, const float* __restrict__ aw,
    unsigned short* __restrict__ nfh, unsigned short* __restrict__ nfm,
    unsigned short* __restrict__ nfl, unsigned short* __restrict__ ht,
    float* __restrict__ EFl, unsigned* __restrict__ EFr)
{
  __shared__ float xl[32][132];
  const int tid = threadIdx.x;
  const int row = tid & 31, g = tid >> 5;
  const int r0 = blockIdx.x * 32;          // global node row base (0..8191)
  const int b = r0 >> 11, n0 = r0 & 2047;
  const int d0 = g * 16;

  float x[16];
  {
    const float* xp = nf + (size_t)(r0 + row) * 128 + d0;
#pragma unroll
    for (int q = 0; q < 4; ++q) {
      float4 v = *(const float4*)(xp + 4 * q);
      x[4*q+0] = v.x; x[4*q+1] = v.y; x[4*q+2] = v.z; x[4*q+3] = v.w;
    }
  }
  unsigned hu[16], mu[16], lu[16];
#pragma unroll
  for (int q = 0; q < 16; ++q) {
    xl[row][d0 + q] = x[q];
    unsigned hb = f2bf(x[q]); float hf = bf2f(hb);
    float r1 = x[q] - hf;
    unsigned mb = f2bf(r1); float mf = bf2f(mb);
    float r2 = r1 - mf;
    unsigned lb = f2bf(r2);
    hu[q] = hb; mu[q] = mb; lu[q] = lb;
  }
  {
    size_t o = (size_t)(r0 + row) * 128 + d0;
    uint4 p0, p1;
    p0.x = hu[0] | (hu[1] << 16);  p0.y = hu[2] | (hu[3] << 16);
    p0.z = hu[4] | (hu[5] << 16);  p0.w = hu[6] | (hu[7] << 16);
    p1.x = hu[8] | (hu[9] << 16);  p1.y = hu[10] | (hu[11] << 16);
    p1.z = hu[12] | (hu[13] << 16); p1.w = hu[14] | (hu[15] << 16);
    *(uint4*)(nfh + o) = p0; *(uint4*)(nfh + o + 8) = p1;
    p0.x = mu[0] | (mu[1] << 16);  p0.y = mu[2] | (mu[3] << 16);
    p0.z = mu[4] | (mu[5] << 16);  p0.w = mu[6] | (mu[7] << 16);
    p1.x = mu[8] | (mu[9] << 16);  p1.y = mu[10] | (mu[11] << 16);
    p1.z = mu[12] | (mu[13] << 16); p1.w = mu[14] | (mu[15] << 16);
    *(uint4*)(nfm + o) = p0; *(uint4*)(nfm + o + 8) = p1;
    p0.x = lu[0] | (lu[1] << 16);  p0.y = lu[2] | (lu[3] << 16);
    p0.z = lu[4] | (lu[5] << 16);  p0.w = lu[6] | (lu[7] << 16);
    p1.x = lu[8] | (lu[9] << 16);  p1.y = lu[10] | (lu[11] << 16);
    p1.z = lu[12] | (lu[13] << 16); p1.w = lu[14] | (lu[15] << 16);
    *(uint4*)(nfl + o) = p0; *(uint4*)(nfl + o + 8) = p1;
  }
  __syncthreads();

  float acc[16];
  const int ob = g * 16;
#pragma unroll
  for (int o = 0; o < 16; ++o) acc[o] = bias[ob + o];
  for (int dd = 0; dd < 128; dd += 4) {
    float4 xq = *(const float4*)&xl[row][dd];
#pragma unroll
    for (int o = 0; o < 16; ++o) {
      float4 wq = *(const float4*)(Wm + (size_t)(ob + o) * 128 + dd);
      acc[o] = fmaf(xq.x, wq.x, acc[o]);
      acc[o] = fmaf(xq.y, wq.y, acc[o]);
      acc[o] = fmaf(xq.z, wq.z, acc[o]);
      acc[o] = fmaf(xq.w, wq.w, acc[o]);
    }
  }
#pragma unroll
  for (int o = 0; o < 16; ++o)
    ht[((size_t)b * 128 + ob + o) * 2048 + n0 + row] = (unsigned short)f2bf(acc[o]);

  const int hh = g >> 1, cb = (g & 1) * 16;
  float sl = 0.f, sr = 0.f;
#pragma unroll
  for (int o = 0; o < 16; ++o) {
    sl = fmaf(acc[o], aw[hh * 64 + cb + o], sl);
    sr = fmaf(acc[o], aw[hh * 64 + 32 + cb + o], sr);
  }
  sl += __shfl_xor(sl, 32, 64);
  sr += __shfl_xor(sr, 32, 64);
  if (!(g & 1)) {
    const float L2E = 1.4426950408889634f;
    float El = exp2f(sl * L2E), Fl = exp2f(sl * (0.3f * L2E));
    float Er = exp2f(sr * L2E), Fr = exp2f(sr * (0.3f * L2E));
    size_t nn = (size_t)(r0 + row);
    EFl[nn * 8 + hh]     = El;
    EFl[nn * 8 + 4 + hh] = Fl;
    EFr[nn * 4 + hh] = (f2bf(Er) << 16) | f2bf(Fr);
  }
}

// ---------------------------------------------------------------------------
// fused attention. All LDS staging via global_load_lds (linear dest, inverse-
// swizzled source). Double-buffered, one barrier per J-tile, zero staging regs.
// S^T via 5-pass split-bf16 MFMA (A-side h/m/l from LDS, B-side h/m in regs).
// LDS map (bytes): A 2x24576 @0 | V 2x8192 @49152 | EF 2x1024 @65536  (67584)
// ---------------------------------------------------------------------------
__global__ __launch_bounds__(256, 2) void gat_attn(
    const unsigned short* __restrict__ nfh, const unsigned short* __restrict__ nfm,
    const unsigned short* __restrict__ nfl, const unsigned short* __restrict__ ht,
    const float* __restrict__ EFl, const unsigned* __restrict__ EFr,
    float* __restrict__ nump, float* __restrict__ denp, const int CH)
{
  __shared__ __align__(16) char sm[67584];
  const int JPC = 2048 / CH, NIT = JPC / 32;

  const int tid  = threadIdx.x;
  const int lane = tid & 63, wv = tid >> 6;
  const int li = lane & 31, hi = lane >> 5;

  // XCD-aware decode: 16 blocks sharing (b,ch) land on one XCD (blk%8 fixed).
  int blk = blockIdx.x, ig, t2;
  if (CH >= 2) {
    int x = blk & 7, y = blk >> 3;
    ig = y & 15;
    t2 = x * (CH >> 1) + (y >> 4);
  } else {
    ig = blk & 15;
    t2 = blk >> 4;
  }
  const int ch = t2 % CH, b = t2 / CH;

  const size_t nb = (size_t)b * 2048;
  const int i0 = ig * 128 + wv * 32;
  const int j0 = ch * JPC;

  // I-side B-fragments (h,m levels only)
  v8s BH[8], BM[8];
  {
    const size_t ro = (nb + i0 + li) * 128 + hi * 8;
#pragma unroll
    for (int kc = 0; kc < 8; ++kc) {
      BH[kc] = *(const v8s*)(nfh + ro + kc * 16);
      BM[kc] = *(const v8s*)(nfm + ro + kc * 16);
    }
  }
  float EL[4], FL[4];
  {
    const float* p = EFl + (nb + i0 + li) * 8;
    float4 e = *(const float4*)p;
    float4 f = *(const float4*)(p + 4);
    EL[0] = e.x; EL[1] = e.y; EL[2] = e.z; EL[3] = e.w;
    FL[0] = f.x; FL[1] = f.y; FL[2] = f.z; FL[3] = f.w;
  }

  v16f acc[4];
#pragma unroll
  for (int h = 0; h < 4; ++h)
#pragma unroll
    for (int r = 0; r < 16; ++r) acc[h][r] = 0.f;
  float den[4] = {0.f, 0.f, 0.f, 0.f};

  // per-lane staging constants
  const int lr = lane >> 4;                         // 0..3 (A rows within 1KB)
  const int aoff_e = ((lane & 15) << 4) ^ (lr << 4);// A within-row src offset, even q
  const int vswz = ((lane & 3) ^ ((lane >> 2) & 3)) << 4; // V src block swizzle

  auto STAGE = [&](int it, int p) {
    const int j = j0 + it * 32;
    const size_t arow = (size_t)(nb + j) * 256;     // byte base of A tile rows
#pragma unroll
    for (int t = 0; t < 6; ++t) {
      const int c = wv * 6 + t, s = c >> 3, q = c & 7;
      const unsigned short* src = (s == 0) ? nfh : (s == 1) ? nfm : nfl;
      const size_t off = arow + (size_t)((q * 4 + lr) * 256 + (aoff_e ^ ((q & 1) << 6)));
      gload16((const char*)src + off, sm + p * 24576 + s * 8192 + q * 1024);
    }
#pragma unroll
    for (int q = 0; q < 2; ++q) {
      const int c = wv * 2 + q;
      const int r = c * 16 + (lane >> 2);
      const size_t srcb = ((size_t)(b * 128 + r) * 2048 + j) * 2 + vswz;
      gload16((const char*)ht + srcb, sm + 49152 + p * 8192 + c * 1024);
    }
    if (wv == 0)  // 1KB (reads 32 rows past tile end; in-bounds of ws)
      gload16((const char*)(EFr + (nb + j + lane) * 4), sm + 65536 + p * 1024);
  };

  STAGE(0, 0);
  __syncthreads();   // implicit vmcnt(0) drain makes buf0 ready

  for (int it = 0; it < NIT; ++it) {
    const int p = it & 1;
    if (it + 1 < NIT) STAGE(it + 1, p ^ 1);   // async, lands by next barrier

    // ---- S^T (5-pass split-bf16) ----
    v16f S;
#pragma unroll
    for (int r = 0; r < 16; ++r) S[r] = 0.f;
    {
      const char* Ab = sm + p * 24576;
      const int abase = li * 256 + hi * 16;
      const int aswz = (li & 7) << 4;
#pragma unroll
      for (int kc = 0; kc < 8; ++kc) {
        const int off = (abase + kc * 32) ^ aswz;
        v8s AH = *(const v8s*)(Ab + off);
        v8s AM = *(const v8s*)(Ab + 8192 + off);
        v8s AL = *(const v8s*)(Ab + 16384 + off);
        S = MFMA32(AH, BH[kc], S);
        S = MFMA32(AH, BM[kc], S);
        S = MFMA32(AM, BH[kc], S);
        S = MFMA32(AM, BM[kc], S);
        S = MFMA32(AL, BH[kc], S);
      }
    }

    // ---- w = mask ? max(El*Er, Fl*Fr) : 0, packed to bf16 pairs ----
    const char* EFb = sm + 65536 + p * 1024;
    unsigned pw[4][8];
#pragma unroll
    for (int rp = 0; rp < 8; ++rp) {
      const int r0i = 2 * rp;
      const int jl0 = (r0i & 3) + 8 * (r0i >> 2) + 4 * hi;
      uint4 e0 = *(const uint4*)(EFb + jl0 * 16);
      uint4 e1 = *(const uint4*)(EFb + (jl0 + 1) * 16);
      const bool m0 = S[r0i] > 0.f;
      const bool m1 = S[r0i + 1] > 0.f;
#pragma unroll
      for (int h = 0; h < 4; ++h) {
        const unsigned u0 = sel4(e0, h), u1 = sel4(e1, h);
        float Er0 = __builtin_bit_cast(float, u0 & 0xFFFF0000u);
        float Fr0 = __builtin_bit_cast(float, u0 << 16);
        float Er1 = __builtin_bit_cast(float, u1 & 0xFFFF0000u);
        float Fr1 = __builtin_bit_cast(float, u1 << 16);
        float w0 = fmaxf(Er0 * EL[h], Fr0 * FL[h]); w0 = m0 ? w0 : 0.f;
        float w1 = fmaxf(Er1 * EL[h], Fr1 * FL[h]); w1 = m1 ? w1 : 0.f;
        den[h] += w0 + w1;
        unsigned pk;
        asm("v_cvt_pk_bf16_f32 %0, %1, %2" : "=v"(pk) : "v"(w0), "v"(w1));
        pw[h][rp] = pk;
      }
    }

    // ---- P fragments via permlane32_swap + PV MFMA ----
    const char* Vb = sm + 49152 + p * 8192;
#pragma unroll
    for (int h = 0; h < 4; ++h) {
      auto r0 = __builtin_amdgcn_permlane32_swap((int)pw[h][0], (int)pw[h][2], false, false);
      auto r1 = __builtin_amdgcn_permlane32_swap((int)pw[h][1], (int)pw[h][3], false, false);
      auto r2 = __builtin_amdgcn_permlane32_swap((int)pw[h][4], (int)pw[h][6], false, false);
      auto r3 = __builtin_amdgcn_permlane32_swap((int)pw[h][5], (int)pw[h][7], false, false);
      uint4 c0, c1;
      c0.x = (unsigned)r0[0]; c0.y = (unsigned)r1[0];
      c0.z = (unsigned)r0[1]; c0.w = (unsigned)r1[1];
      c1.x = (unsigned)r2[0]; c1.y = (unsigned)r3[0];
      c1.z = (unsigned)r2[1]; c1.w = (unsigned)r3[1];
      v8s P0 = __builtin_bit_cast(v8s, c0);
      v8s P1 = __builtin_bit_cast(v8s, c1);
      const int r = h * 32 + li, r3m = li & 3;
      const char* vr = Vb + r * 64;
      v8s V0 = *(const v8s*)(vr + ((hi ^ r3m) << 4));
      v8s V1 = *(const v8s*)(vr + (((2 + hi) ^ r3m) << 4));
      acc[h] = MFMA32(P0, V0, acc[h]);
      acc[h] = MFMA32(P1, V1, acc[h]);
    }
    __syncthreads();   // drains STAGE(it+1) gloads; fences buffer reuse
  }

#pragma unroll
  for (int h = 0; h < 4; ++h) den[h] += __shfl_xor(den[h], 32, 64);

  const size_t obase = ((size_t)b * CH + ch) * 2048 + i0;
#pragma unroll
  for (int h = 0; h < 4; ++h) {
#pragma unroll
    for (int r = 0; r < 16; ++r) {
      const int il = (r & 3) + 8 * (r >> 2) + 4 * hi;
      nump[(obase + il) * 128 + h * 32 + li] = acc[h][r];
    }
  }
  if (lane < 32) {
    float4 dv;
    dv.x = den[0]; dv.y = den[1]; dv.z = den[2]; dv.w = den[3];
    *(float4*)(denp + (obase + li) * 4) = dv;
  }
}

// ---------------------------------------------------------------------------
// reduce: out = (sum_ch num) / (sum_ch den)
// ---------------------------------------------------------------------------
__global__ __launch_bounds__(256) void gat_reduce(
    const float* __restrict__ nump, const float* __restrict__ denp,
    float* __restrict__ out, const int CH)
{
  const int idx = blockIdx.x * 256 + threadIdx.x;   // < 4*2048*128
  const int b = idx >> 18;
  const int rem = idx & 262143;
  const int n = rem >> 7;
  const int col = rem & 127;
  const int h = col >> 5;
  float s = 0.f, d = 0.f;
  for (int ch = 0; ch < CH; ++ch) {
    s += nump[(((size_t)b * CH + ch) * 2048 + n) * 128 + col];
    d += denp[(((size_t)b * CH + ch) * 2048 + n) * 4 + h];
  }
  out[idx] = s / d;
}

// ---------------------------------------------------------------------------
extern "C" void kernel_launch(void* const* d_in, const int* in_sizes, int n_in,
                              void* d_out, int out_size, void* d_ws, size_t ws_size,
                              hipStream_t stream) {
  const float* nf   = (const float*)d_in[0];
  const float* Wm   = (const float*)d_in[1];
  const float* bias = (const float*)d_in[2];
  const float* aw   = (const float*)d_in[3];
  float* out = (float*)d_out;
  char* ws = (char*)d_ws;

  const size_t S1 = 8192ull * 128 * 2;              // 2 MB per bf16 array
  unsigned short* nfh = (unsigned short*)(ws);
  unsigned short* nfm = (unsigned short*)(ws + S1);
  unsigned short* nfl = (unsigned short*)(ws + 2 * S1);
  unsigned short* ht  = (unsigned short*)(ws + 3 * S1);
  float*    EFl = (float*)(ws + 4 * S1);            // 8192*8*4  = 262144
  unsigned* EFr = (unsigned*)(ws + 4 * S1 + 262144);// 8192*4*4  = 131072
  const size_t fixed = 4 * S1 + 262144 + 131072;    // 8,781,824
  const size_t per = 4194304ull + 131072ull;        // num + den per chunk

  int CH = 1;
  if      (ws_size >= fixed + 8 * per) CH = 8;
  else if (ws_size >= fixed + 4 * per) CH = 4;
  else if (ws_size >= fixed + 2 * per) CH = 2;

  float* denp = (float*)(ws + fixed);
  float* nump = (float*)(ws + fixed + (size_t)CH * 131072);

  gat_prep<<<256, 256, 0, stream>>>(nf, Wm, bias, aw, nfh, nfm, nfl, ht, EFl, EFr);
  gat_attn<<<64 * CH, 256, 0, stream>>>(nfh, nfm, nfl, ht, EFl, EFr, nump, denp, CH);
  gat_reduce<<<4096, 256, 0, stream>>>(nump, denp, out, CH);
}